// Round 9
// baseline (137.113 us; speedup 1.0000x reference)
//
#include <hip/hip_runtime.h>
#include <math.h>

// Shapes: B=32 T=64 N=16 A=20 D=128 S=32 E=64 H=256; batch=2048
// 3-launch pipeline:
//  k1: blocks 0..319  : X(2048x128) @ [W1a|Wfa|Wb|Wv1] -> h1(bf16), hf, b1buf, vrelu
//                       (whole-K LDS tile, ONE barrier; A-tile rotation-swizzled)
//      blocks 320..639: W1b -> Bp bf16 fragment-packed
//  k2: blocks 0..319  : w1 = |h1 @ W1b + b1b|  MFMA bf16 128x128 tiles -> bf16
//      blocks 320..575: wf = |hf @ Wfb + bfb|
//  k3: 512 blocks x 256 thr, 4 batches/block: coalition bitmasks + hidden/elu + q_tot
// out: q_tot (2048) ++ w_est (2048*16), fp32

#define BATCH 2048

typedef __attribute__((ext_vector_type(8))) short bf16x8;
typedef __attribute__((ext_vector_type(4))) float f32x4;

__device__ inline unsigned short f2bf(float f) {
    unsigned int u = __float_as_uint(f);
    unsigned int r = (u + 0x7FFFu + ((u >> 16) & 1u)) >> 16;
    return (unsigned short)r;
}
__device__ inline float bf2f(unsigned short s) {
    return __uint_as_float(((unsigned int)s) << 16);
}
// A-tile swizzle: element A[m][k] lives at As[m][(k + 4*m) & 127].
// Same formula at store & load; k multiple of 4 keeps 16B alignment.
__device__ inline int aswz(int m, int k) { return (k + 4 * m) & 127; }

// ---------------- k1: first-layer GEMM (whole-K LDS) + Bp pack ----------------
__global__ __launch_bounds__(256) void k1(
    const float* __restrict__ X,
    const float* __restrict__ W1a, const float* __restrict__ b1a,
    const float* __restrict__ Wfa, const float* __restrict__ bfa,
    const float* __restrict__ Wb,  const float* __restrict__ bb,
    const float* __restrict__ Wv1, const float* __restrict__ bv1,
    const float* __restrict__ W1b,
    unsigned short* __restrict__ h1_bf, float* __restrict__ hf,
    float* __restrict__ b1buf, float* __restrict__ vrelu,
    unsigned short* __restrict__ Bp)
{
    __shared__ float As[64][128];   // 32 KB, A[m][k] rotation-swizzled
    __shared__ float Bs[128][64];   // 32 KB, W[k][n]
    const int t = threadIdx.x, bid = blockIdx.x;

    if (bid >= 320) {
        // Bp[((nb*8+kc)*4+kg)*1024 + n_local*8 + j] = bf16(W1b[(kc*32+kg*8+j)*2560 + nb*128+n_local])
        int idx = (bid - 320) * 256 + t;  // 0..81919
        int n_local = idx & 127;
        int g = idx >> 7;
        int kg = g & 3, kcn = g >> 2;
        int kc = kcn & 7, nb = kcn >> 3;
        int kbase = kc * 32 + kg * 8;
        int col = nb * 128 + n_local;
        unsigned short o[8];
        #pragma unroll
        for (int j = 0; j < 8; ++j)
            o[j] = f2bf(W1b[(kbase + j) * 2560 + col]);
        *(uint4*)&Bp[idx * 8] = *(uint4*)o;
        return;
    }

    const int nb = bid % 10, mb = bid / 10;
    const int m0 = mb * 64, n0 = nb * 64;
    const int tx = t & 15, ty = t >> 4;

    const float* Wsrc; const float* bsrc; int ldb, c0;
    if (nb < 4)       { Wsrc = W1a; bsrc = b1a; ldb = 256; c0 = n0; }
    else if (nb < 8)  { Wsrc = Wfa; bsrc = bfa; ldb = 256; c0 = n0 - 256; }
    else if (nb == 8) { Wsrc = Wb;  bsrc = bb;  ldb = 64;  c0 = 0; }
    else              { Wsrc = Wv1; bsrc = bv1; ldb = 64;  c0 = 0; }

    // stage A: 64 rows x 32 float4 = 2048 f4, 8 per thread (swizzled position)
    #pragma unroll
    for (int c = 0; c < 8; ++c) {
        int idx = t + c * 256;
        int row = idx >> 5, f4c = idx & 31;
        float4 v = *(const float4*)&X[(m0 + row) * 128 + f4c * 4];
        *(float4*)&As[row][aswz(row, f4c * 4)] = v;
    }
    // stage B: 128 rows x 16 float4 = 2048 f4, 8 per thread
    #pragma unroll
    for (int c = 0; c < 8; ++c) {
        int idx = t + c * 256;
        int row = idx >> 4, f4c = idx & 15;
        *(float4*)&Bs[row][f4c * 4] = *(const float4*)&Wsrc[row * ldb + c0 + f4c * 4];
    }
    __syncthreads();

    float acc[4][4] = {{0}};
    for (int kb = 0; kb < 128; kb += 4) {
        float av[4][4], bv4[4][4];
        #pragma unroll
        for (int i = 0; i < 4; ++i) {
            int m = ty * 4 + i;
            float4 v = *(const float4*)&As[m][aswz(m, kb)];
            av[i][0] = v.x; av[i][1] = v.y; av[i][2] = v.z; av[i][3] = v.w;
        }
        #pragma unroll
        for (int kk = 0; kk < 4; ++kk) {
            float4 v = *(const float4*)&Bs[kb + kk][tx * 4];
            bv4[kk][0] = v.x; bv4[kk][1] = v.y; bv4[kk][2] = v.z; bv4[kk][3] = v.w;
        }
        #pragma unroll
        for (int kk = 0; kk < 4; ++kk)
            #pragma unroll
            for (int i = 0; i < 4; ++i)
                #pragma unroll
                for (int j = 0; j < 4; ++j)
                    acc[i][j] = fmaf(av[i][kk], bv4[kk][j], acc[i][j]);
    }

    const int ncol = c0 + tx * 4;
    float4 bias = *(const float4*)&bsrc[ncol];
    #pragma unroll
    for (int i = 0; i < 4; ++i) {
        int m = m0 + ty * 4 + i;
        float v0 = acc[i][0] + bias.x, v1 = acc[i][1] + bias.y;
        float v2 = acc[i][2] + bias.z, v3 = acc[i][3] + bias.w;
        if (nb < 4) {
            ushort4 o;
            o.x = f2bf(fmaxf(v0, 0.f)); o.y = f2bf(fmaxf(v1, 0.f));
            o.z = f2bf(fmaxf(v2, 0.f)); o.w = f2bf(fmaxf(v3, 0.f));
            *(ushort4*)&h1_bf[m * 256 + ncol] = o;
        } else if (nb < 8) {
            float4 o = { fmaxf(v0,0.f), fmaxf(v1,0.f), fmaxf(v2,0.f), fmaxf(v3,0.f) };
            *(float4*)&hf[m * 256 + ncol] = o;
        } else if (nb == 8) {
            float4 o = { v0, v1, v2, v3 };
            *(float4*)&b1buf[m * 64 + ncol] = o;
        } else {
            float4 o = { fmaxf(v0,0.f), fmaxf(v1,0.f), fmaxf(v2,0.f), fmaxf(v3,0.f) };
            *(float4*)&vrelu[m * 64 + ncol] = o;
        }
    }
}

// ---------------- k2: MFMA GEMM w1 (blocks 0..319) + wf (blocks 320..575) ----------------
#define AS_STRIDE 40
__global__ __launch_bounds__(256) void k2(
    const unsigned short* __restrict__ A, const unsigned short* __restrict__ Bp,
    const float* __restrict__ bias, unsigned short* __restrict__ C,
    const float* __restrict__ hf, const float* __restrict__ Wfb,
    const float* __restrict__ bfb, float* __restrict__ wf)
{
    __shared__ __align__(16) char smem[18432];
    const int t = threadIdx.x, bid = blockIdx.x;

    if (bid < 320) {
        unsigned short* As = (unsigned short*)smem;            // 128 x 40 bf16, 10240B
        unsigned short* Bs = (unsigned short*)(smem + 10240);  // 4096 bf16, 8192B
        const int lane = t & 63, wave = t >> 6;
        const int ln15 = lane & 15, q4 = lane >> 4;
        const int nb = bid % 20, m0 = (bid / 20) * 128, n0 = nb * 128;
        const int wm = (wave & 1) * 64, wn = (wave >> 1) * 64;

        f32x4 acc[4][4];
        #pragma unroll
        for (int i = 0; i < 4; ++i)
            #pragma unroll
            for (int j = 0; j < 4; ++j)
                acc[i][j] = (f32x4){0.f, 0.f, 0.f, 0.f};

        for (int kc = 0; kc < 8; ++kc) {
            #pragma unroll
            for (int c = 0; c < 2; ++c) {
                int ch = t + c * 256;
                int row = ch >> 2, part = ch & 3;
                *(uint4*)&As[row * AS_STRIDE + part * 8] =
                    *(const uint4*)&A[(m0 + row) * 256 + kc * 32 + part * 8];
            }
            {
                const uint4* src = (const uint4*)&Bp[(nb * 8 + kc) * 4096];
                ((uint4*)Bs)[t] = src[t];
                ((uint4*)Bs)[t + 256] = src[t + 256];
            }
            __syncthreads();
            bf16x8 af[4], bfr[4];
            #pragma unroll
            for (int mi = 0; mi < 4; ++mi)
                af[mi] = *(const bf16x8*)&As[(wm + mi * 16 + ln15) * AS_STRIDE + q4 * 8];
            #pragma unroll
            for (int ni = 0; ni < 4; ++ni)
                bfr[ni] = *(const bf16x8*)&Bs[(q4 * 128 + wn + ni * 16 + ln15) * 8];
            #pragma unroll
            for (int mi = 0; mi < 4; ++mi)
                #pragma unroll
                for (int ni = 0; ni < 4; ++ni)
                    acc[mi][ni] = __builtin_amdgcn_mfma_f32_16x16x32_bf16(af[mi], bfr[ni], acc[mi][ni], 0, 0, 0);
            __syncthreads();
        }
        #pragma unroll
        for (int ni = 0; ni < 4; ++ni) {
            int col = n0 + wn + ni * 16 + ln15;
            float bv = bias[col];
            #pragma unroll
            for (int mi = 0; mi < 4; ++mi) {
                #pragma unroll
                for (int j = 0; j < 4; ++j) {
                    int row = m0 + wm + mi * 16 + q4 * 4 + j;
                    C[row * 2560 + col] = f2bf(fabsf(acc[mi][ni][j] + bv));
                }
            }
        }
    } else {
        float* hfs  = (float*)smem;            // [8][64], 2KB
        float* wfbs = (float*)(smem + 2048);   // [64][64], 16KB
        const int e = t & 63, mg = t >> 6;
        const int b0 = (bid - 320) * 8;
        float acc0 = 0.f, acc1 = 0.f;

        for (int kc = 0; kc < 4; ++kc) {
            for (int i = t; i < 1024; i += 256)
                ((float4*)wfbs)[i] = ((const float4*)(Wfb + kc * 64 * 64))[i];
            if (t < 128) {
                int r = t >> 4, p = t & 15;
                ((float4*)hfs)[t] = *(const float4*)&hf[(b0 + r) * 256 + kc * 64 + p * 4];
            }
            __syncthreads();
            #pragma unroll 8
            for (int k = 0; k < 64; ++k) {
                float wv = wfbs[k * 64 + e];
                acc0 = fmaf(hfs[mg * 64 + k], wv, acc0);
                acc1 = fmaf(hfs[(mg + 4) * 64 + k], wv, acc1);
            }
            __syncthreads();
        }
        float bf = bfb[e];
        wf[(b0 + mg) * 64 + e]     = fabsf(acc0 + bf);
        wf[(b0 + mg + 4) * 64 + e] = fabsf(acc1 + bf);
    }
}

// ---------------- k3: 4 batches/block, coalition + hidden/elu + q_tot ----------------
__global__ __launch_bounds__(256) void k3(
    const float* __restrict__ actions, const int* __restrict__ gc,
    const unsigned short* __restrict__ w1, const float* __restrict__ b1buf,
    const float* __restrict__ wf, const float* __restrict__ vrelu,
    const float* __restrict__ Wv2, const float* __restrict__ bv2,
    const float* __restrict__ agent_qs, float* __restrict__ out)
{
    __shared__ unsigned short w1s[4][2560];   // all 40 rows x 64, 20 KB
    __shared__ float ins[4][16][20];          // 5 KB
    __shared__ int aidx[4][16];
    __shared__ int q[4][32][16];              // 8 KB
    __shared__ unsigned int msk[4][32][20];   // 10 KB
    const int t = threadIdx.x;
    const int b0 = blockIdx.x * 4;

    // phase A: loads (all threads busy)
    #pragma unroll
    for (int r = 0; r < 5; ++r) {             // w1 tiles: 4 x 320 uint4
        int idx = t + r * 256;
        int bb = idx / 320, off = idx % 320;
        ((uint4*)w1s[bb])[off] = ((const uint4*)(w1 + (b0 + bb) * 2560))[off];
    }
    #pragma unroll
    for (int r = 0; r < 2; ++r) {             // gc: 4 x 128 uint4
        int idx = t + r * 256;
        int bb = idx >> 7, off = idx & 127;
        ((uint4*)q[bb])[off] = ((const uint4*)(gc + (b0 + bb) * 512))[off];
    }
    #pragma unroll
    for (int r = 0; r < 3; ++r) {             // msk zero: 640 uint4 total
        int idx = t + r * 256;
        if (idx < 640) ((uint4*)msk)[idx] = make_uint4(0u, 0u, 0u, 0u);
    }
    #pragma unroll
    for (int r = 0; r < 5; ++r) {             // actions -> aidx: 4 x 320
        int idx = t + r * 256;
        int bb = idx / 320, u = idx % 320;
        float av = actions[(b0 + bb) * 320 + u];
        if (av > 0.5f) aidx[bb][u / 20] = u % 20;
    }
    __syncthreads();

    // phase B: masks, 4 x 512 atomicOr = 8 per thread
    #pragma unroll
    for (int r = 0; r < 8; ++r) {
        int u = t + r * 256;                  // 0..2047
        int bb = u >> 9, s = (u >> 4) & 31, j = u & 15;
        atomicOr(&msk[bb][s][aidx[bb][q[bb][s][j]]], 1u << j);
    }
    __syncthreads();

    // phase C: coal, 4 x 320 tasks = 5 per thread
    #pragma unroll
    for (int r = 0; r < 5; ++r) {
        int u = t + r * 256;
        int bb = u / 320, v = u % 320;
        int i = v / 20, a = v % 20;
        float acc = 0.f;
        #pragma unroll 8
        for (int s = 0; s < 32; ++s) {
            int g = q[bb][s][i];
            acc += (float)(g * __popc(msk[bb][s][a] & ((1u << g) - 1u)));
        }
        ins[bb][i][a] = acc * (1.0f / 512.0f);
    }
    __syncthreads();

    // phase D: one wave per batch, agents serial
    const int wv = t >> 6, e = t & 63;
    const int b = b0 + wv;
    const float b1v = b1buf[b * 64 + e];
    const float wfv = wf[b * 64 + e];
    const float vv  = vrelu[b * 64 + e] * Wv2[e];
    const float aq  = (e < 16) ? agent_qs[b * 16 + e] : 0.f;
    const float bv2v = bv2[0];
    float qtot = 0.f;
    for (int i = 0; i < 16; ++i) {
        float acc = b1v;
        #pragma unroll
        for (int k = 0; k < 20; ++k)
            acc = fmaf(ins[wv][i][k], bf2f(w1s[wv][k * 64 + e]), acc);
        acc += bf2f(w1s[wv][(20 + aidx[wv][i]) * 64 + e]);  // one-hot action row
        float hidden = acc > 0.f ? acc : expm1f(acc);
        float p = hidden * wfv + vv;
        #pragma unroll
        for (int off = 32; off > 0; off >>= 1)
            p += __shfl_down(p, off, 64);
        float aqi = __shfl(aq, i, 64);
        if (e == 0) {
            float west = fabsf(p + bv2v);
            out[2048 + b * 16 + i] = west;
            qtot = fmaf(west, aqi, qtot);
        }
    }
    if (e == 0) out[b] = qtot;
}

extern "C" void kernel_launch(void* const* d_in, const int* in_sizes, int n_in,
                              void* d_out, int out_size, void* d_ws, size_t ws_size,
                              hipStream_t stream) {
    const float* states   = (const float*)d_in[0];
    const float* actions  = (const float*)d_in[1];
    const float* agent_qs = (const float*)d_in[2];
    const int*   gc       = (const int*)d_in[4];
    const float* W1a = (const float*)d_in[5];
    const float* b1a = (const float*)d_in[6];
    const float* W1b = (const float*)d_in[7];
    const float* b1b = (const float*)d_in[8];
    const float* Wb  = (const float*)d_in[9];
    const float* bb  = (const float*)d_in[10];
    const float* Wfa = (const float*)d_in[11];
    const float* bfa = (const float*)d_in[12];
    const float* Wfb = (const float*)d_in[13];
    const float* bfb = (const float*)d_in[14];
    const float* Wv1 = (const float*)d_in[15];
    const float* bv1 = (const float*)d_in[16];
    const float* Wv2 = (const float*)d_in[17];
    const float* bv2 = (const float*)d_in[18];

    float* ws     = (float*)d_ws;
    float* hf     = ws;                      // 524288 f
    float* b1buf  = hf + 524288;             // 131072 f
    float* vrelu  = b1buf + 131072;          // 131072 f
    float* wfbuf  = vrelu + 131072;          // 131072 f
    unsigned short* h1_bf = (unsigned short*)(wfbuf + 131072); // 524288 us
    unsigned short* Bp    = h1_bf + 524288;                    // 655360 us
    unsigned short* w1    = Bp + 655360;                       // 5242880 us
    float* out = (float*)d_out;

    k1<<<640, 256, 0, stream>>>(states, W1a, b1a, Wfa, bfa, Wb, bb, Wv1, bv1,
                                W1b, h1_bf, hf, b1buf, vrelu, Bp);
    k2<<<576, 256, 0, stream>>>(h1_bf, Bp, b1b, w1, hf, Wfb, bfb, wfbuf);
    k3<<<512, 256, 0, stream>>>(actions, gc, w1, b1buf, wfbuf, vrelu,
                                Wv2, bv2, agent_qs, out);
}